// Round 1
// baseline (415.853 us; speedup 1.0000x reference)
//
#include <hip/hip_runtime.h>
#include <math.h>

#define BB 32
#define SS 8192
#define DD 256
#define K_SEL 1638            // max(1, int(8192*0.2))
#define EMPH 1.5f
#define NCHUNK 64
#define ROWS_PER_BLOCK (SS / NCHUNK)   // 128

// ---------------- K1: e[b,s] = tanh(x[b,s,:]·W + bias) ----------------
// wave per row: lane l holds W[4l..4l+3]; one float4 x-load per lane per row.
__global__ __launch_bounds__(256) void k1_dot_tanh(const float* __restrict__ x,
                                                   const float* __restrict__ W,
                                                   const float* __restrict__ bias,
                                                   float* __restrict__ e) {
    const int lane = threadIdx.x & 63;
    const int wib  = threadIdx.x >> 6;
    const int wavesPerBlock = blockDim.x >> 6;
    const int waveId = blockIdx.x * wavesPerBlock + wib;
    const int totalWaves = gridDim.x * wavesPerBlock;
    const float4 w4 = ((const float4*)W)[lane];
    const float bias0 = bias[0];
    const int totalRows = BB * SS;
    for (int row = waveId; row < totalRows; row += totalWaves) {
        float4 x4 = ((const float4*)(x + (size_t)row * DD))[lane];
        float p = x4.x * w4.x + x4.y * w4.y + x4.z * w4.z + x4.w * w4.w;
        #pragma unroll
        for (int off = 32; off >= 1; off >>= 1)
            p += __shfl_xor(p, off, 64);
        if (lane == 0) e[row] = tanhf(p + bias0);
    }
}

// ---------------- K2: per-batch softmax + exact top-k emphasis ----------------
// One block (1024 threads) per batch. In-place: reads e, writes emphasized_a.
__global__ __launch_bounds__(1024) void k2_softmax_topk(float* __restrict__ ea) {
    const int b = blockIdx.x;
    const int tid = threadIdx.x;
    const int lane = tid & 63;
    const int wid  = tid >> 6;

    __shared__ float se[SS];          // 32 KB
    __shared__ float wredf[16];
    __shared__ unsigned hist[256];
    __shared__ unsigned ssum[256];
    __shared__ unsigned wcnt[16];
    __shared__ unsigned uvar[3];      // 0: selBin, 1: kkNext, 2: runningEqBase
    __shared__ float fvar[2];         // 0: max, 1: invZ

    float* eg = ea + (size_t)b * SS;

    // load + local max
    float lmax = -3.0e38f;
    #pragma unroll
    for (int i = 0; i < 8; i++) {
        int s = tid + i * 1024;
        float v = eg[s];
        se[s] = v;
        lmax = fmaxf(lmax, v);
    }
    #pragma unroll
    for (int off = 32; off >= 1; off >>= 1)
        lmax = fmaxf(lmax, __shfl_xor(lmax, off, 64));
    if (lane == 0) wredf[wid] = lmax;
    __syncthreads();
    if (tid == 0) {
        float m = wredf[0];
        for (int w = 1; w < 16; w++) m = fmaxf(m, wredf[w]);
        fvar[0] = m;
    }
    __syncthreads();
    const float m = fvar[0];

    // sum of exp(e - m)
    float lsum = 0.0f;
    #pragma unroll
    for (int i = 0; i < 8; i++) {
        int s = tid + i * 1024;
        lsum += expf(se[s] - m);
    }
    #pragma unroll
    for (int off = 32; off >= 1; off >>= 1)
        lsum += __shfl_xor(lsum, off, 64);
    if (lane == 0) wredf[wid] = lsum;
    __syncthreads();
    if (tid == 0) {
        float z = 0.0f;
        for (int w = 0; w < 16; w++) z += wredf[w];
        fvar[1] = 1.0f / z;
    }
    __syncthreads();
    const float invZ = fvar[1];

    // radix select: find key of k-th largest e (order of a == order of e)
    unsigned kk = K_SEL;
    unsigned prefix = 0;
    for (int byte = 3; byte >= 0; byte--) {
        if (tid < 256) hist[tid] = 0;
        __syncthreads();
        #pragma unroll
        for (int i = 0; i < 8; i++) {
            int s = tid + i * 1024;
            unsigned u = __float_as_uint(se[s]);
            unsigned key = u ^ ((u & 0x80000000u) ? 0xFFFFFFFFu : 0x80000000u);
            bool active = (byte == 3) || ((key >> ((byte + 1) * 8)) == prefix);
            if (active) atomicAdd(&hist[(key >> (byte * 8)) & 0xFFu], 1u);
        }
        __syncthreads();
        if (tid < 256) ssum[tid] = hist[tid];
        __syncthreads();
        // inclusive suffix scan over 256 bins
        for (int off = 1; off < 256; off <<= 1) {
            unsigned add = 0;
            if (tid < 256 && tid + off < 256) add = ssum[tid + off];
            __syncthreads();
            if (tid < 256) ssum[tid] += add;
            __syncthreads();
        }
        if (tid < 256) {
            unsigned above = (tid == 255) ? 0u : ssum[tid + 1];
            if (above < kk && kk <= ssum[tid]) {
                uvar[0] = (unsigned)tid;
                uvar[1] = kk - above;
            }
        }
        __syncthreads();
        prefix = (prefix << 8) | uvar[0];
        kk = uvar[1];
        __syncthreads();
    }
    const unsigned T = prefix;   // key of the k-th largest value
    const unsigned r = kk;       // how many elements equal to T belong in top-k

    // selection + write; ties broken by lowest index (stable, matches lax.top_k)
    if (tid == 0) uvar[2] = 0;
    __syncthreads();
    for (int chunk = 0; chunk < 8; chunk++) {
        int s = chunk * 1024 + tid;
        float v = se[s];
        unsigned u = __float_as_uint(v);
        unsigned key = u ^ ((u & 0x80000000u) ? 0xFFFFFFFFu : 0x80000000u);
        bool gt = key > T;
        bool eq = (key == T);
        unsigned long long bal = __ballot(eq);
        unsigned waveTot = (unsigned)__popcll(bal);
        unsigned myPref = (unsigned)__popcll(bal & ((1ull << lane) - 1ull));
        if (lane == 0) wcnt[wid] = waveTot;
        __syncthreads();
        unsigned base = uvar[2];
        for (int w = 0; w < wid; w++) base += wcnt[w];
        unsigned rank = base + myPref;
        bool sel = gt || (eq && rank < r);
        float a = expf(v - m) * invZ;
        eg[s] = sel ? a * EMPH : a;
        __syncthreads();
        if (tid == 0) {
            unsigned t = uvar[2];
            for (int w = 0; w < 16; w++) t += wcnt[w];
            uvar[2] = t;
        }
        __syncthreads();
    }
}

// ---------------- K3: partial weighted sums (ws path) ----------------
// block = one (b, s-chunk). wave per row stepping by 4; lane owns 4 columns.
__global__ __launch_bounds__(256) void k3_weighted_partial(const float* __restrict__ x,
                                                           const float* __restrict__ ea,
                                                           float* __restrict__ part) {
    const int blk = blockIdx.x;               // b*NCHUNK + chunk
    const int b = blk / NCHUNK;
    const int chunk = blk % NCHUNK;
    const int lane = threadIdx.x & 63;
    const int wid  = threadIdx.x >> 6;
    const float* xb = x + ((size_t)b * SS + (size_t)chunk * ROWS_PER_BLOCK) * DD;
    const float* ab = ea + (size_t)b * SS + (size_t)chunk * ROWS_PER_BLOCK;
    float4 acc = make_float4(0.f, 0.f, 0.f, 0.f);
    for (int rr = wid; rr < ROWS_PER_BLOCK; rr += 4) {
        float4 x4 = ((const float4*)(xb + (size_t)rr * DD))[lane];
        float a = ab[rr];
        acc.x += x4.x * a; acc.y += x4.y * a; acc.z += x4.z * a; acc.w += x4.w * a;
    }
    __shared__ float lds[4 * 256];
    ((float4*)lds)[wid * 64 + lane] = acc;
    __syncthreads();
    const int t = threadIdx.x;
    float v = lds[0 * 256 + t] + lds[1 * 256 + t] + lds[2 * 256 + t] + lds[3 * 256 + t];
    part[(size_t)blk * 256 + t] = v;
}

// K3 fallback: atomics directly into d_out (needs zeroed out region)
__global__ __launch_bounds__(256) void k0_zero(float* __restrict__ p, int n) {
    int i = blockIdx.x * blockDim.x + threadIdx.x;
    if (i < n) p[i] = 0.0f;
}
__global__ __launch_bounds__(256) void k3_weighted_atomic(const float* __restrict__ x,
                                                          const float* __restrict__ ea,
                                                          float* __restrict__ out) {
    const int blk = blockIdx.x;
    const int b = blk / NCHUNK;
    const int chunk = blk % NCHUNK;
    const int lane = threadIdx.x & 63;
    const int wid  = threadIdx.x >> 6;
    const float* xb = x + ((size_t)b * SS + (size_t)chunk * ROWS_PER_BLOCK) * DD;
    const float* ab = ea + (size_t)b * SS + (size_t)chunk * ROWS_PER_BLOCK;
    float4 acc = make_float4(0.f, 0.f, 0.f, 0.f);
    for (int rr = wid; rr < ROWS_PER_BLOCK; rr += 4) {
        float4 x4 = ((const float4*)(xb + (size_t)rr * DD))[lane];
        float a = ab[rr];
        acc.x += x4.x * a; acc.y += x4.y * a; acc.z += x4.z * a; acc.w += x4.w * a;
    }
    __shared__ float lds[4 * 256];
    ((float4*)lds)[wid * 64 + lane] = acc;
    __syncthreads();
    const int t = threadIdx.x;
    float v = lds[0 * 256 + t] + lds[1 * 256 + t] + lds[2 * 256 + t] + lds[3 * 256 + t];
    atomicAdd(&out[b * 256 + t], v);
}

// ---------------- K4: reduce partials ----------------
__global__ __launch_bounds__(256) void k4_reduce(const float* __restrict__ part,
                                                 float* __restrict__ out) {
    const int b = blockIdx.x;
    const int d = threadIdx.x;
    float s = 0.0f;
    for (int c = 0; c < NCHUNK; c++)
        s += part[((size_t)b * NCHUNK + c) * 256 + d];
    out[b * 256 + d] = s;
}

extern "C" void kernel_launch(void* const* d_in, const int* in_sizes, int n_in,
                              void* d_out, int out_size, void* d_ws, size_t ws_size,
                              hipStream_t stream) {
    const float* x    = (const float*)d_in[0];
    const float* W    = (const float*)d_in[1];
    const float* bias = (const float*)d_in[2];
    float* out = (float*)d_out;
    float* sum_out = out;             // [B, D]
    float* ea = out + BB * DD;        // [B, S] (e first, then emphasized_a in place)

    k1_dot_tanh<<<4096, 256, 0, stream>>>(x, W, bias, ea);
    k2_softmax_topk<<<BB, 1024, 0, stream>>>(ea);

    const size_t part_bytes = (size_t)BB * NCHUNK * 256 * sizeof(float); // 2 MB
    if (ws_size >= part_bytes) {
        float* part = (float*)d_ws;
        k3_weighted_partial<<<BB * NCHUNK, 256, 0, stream>>>(x, ea, part);
        k4_reduce<<<BB, 256, 0, stream>>>(part, sum_out);
    } else {
        k0_zero<<<(BB * DD + 255) / 256, 256, 0, stream>>>(sum_out, BB * DD);
        k3_weighted_atomic<<<BB * NCHUNK, 256, 0, stream>>>(x, ea, sum_out);
    }
}